// Round 12
// baseline (202.689 us; speedup 1.0000x reference)
//
#include <hip/hip_runtime.h>

// B=64, S=512, D=256, VOCAB=50000, NC=10, N_STEPS=10 (h=0.1), BN eval.
// z_final = z0 @ P10 + c10, P10 = M^10, M = Taylor4(exp(hA)), A = W^T.
// Transpose trick: M = N^T, N = I + B, B = 0.1W + 0.005W^2 + (1e-3/6)W^3 + (1e-4/24)W^4.
// Squared-binomial: D = N^2 - I = 2B + B^2; N^10 = sum C(5,k) D^k;
// ctot = V c1b, V = sum C(5,k+1) D^k, c1b = 2c1 + B c1.
//
// LESSONS (R1-R11):
//  - Intra-kernel global sync: 70-110us/event. Multi-dispatch only.
//  - 1024-thread blocks cap VGPR at 64 -> spills. 256-thread prep blocks.
//  - k_main depth-4 B pipeline: regression vs depth-2 (R11). Keep depth-2.
//  - k_main pipes: LDS-A 18us, L2-B 13us, MFMA 11us vs measured 46.5 ->
//    latency-bound at 2 waves/SIMD (grid 512 = occupancy-limited by GRID).
//  - THIS ROUND: grid 1024 (M=32/block) -> 4 waves/SIMD; batch-major block
//    map (all chunks of a batch on one XCD -> emb L2-local); T5 setprio
//    around MFMA (barrier-free drifting waves = attn-like regime, m191).

typedef short bf16x8 __attribute__((ext_vector_type(8)));
typedef float f32x4 __attribute__((ext_vector_type(4)));

__device__ __forceinline__ unsigned short f2bf(float f) {
  unsigned u = __float_as_uint(f);
  u += 0x7FFFu + ((u >> 16) & 1u);   // RNE; inputs are normal floats
  return (unsigned short)(u >> 16);
}

// acc = sum_k xrow[k] * Y[k][c]; xrow in LDS, Y global row-major, coalesced
// across c. Windows of 64 loads fully in VGPRs (256-thread blocks only!).
__device__ __forceinline__ float dotcol64(const float* __restrict__ xrow,
                                          const float* __restrict__ Y, int c) {
  float a0 = 0.f, a1 = 0.f, a2 = 0.f, a3 = 0.f;
#pragma unroll 1
  for (int w = 0; w < 4; ++w) {
    float bv[64];
#pragma unroll
    for (int v = 0; v < 64; ++v) bv[v] = Y[(w * 64 + v) * 256 + c];
#pragma unroll
    for (int v = 0; v < 64; v += 4) {
      a0 = fmaf(xrow[w * 64 + v + 0], bv[v + 0], a0);
      a1 = fmaf(xrow[w * 64 + v + 1], bv[v + 1], a1);
      a2 = fmaf(xrow[w * 64 + v + 2], bv[v + 2], a2);
      a3 = fmaf(xrow[w * 64 + v + 3], bv[v + 3], a3);
    }
  }
  return (a0 + a1) + (a2 + a3);
}

// ---- d1: blocks 0-255: W-power row chain -> B row + c1[i].
//          blocks 256-639: conv repack (consecutive-kd lanes) + featbuf zero.
__global__ __launch_bounds__(256) void k_prep1(
    const float* __restrict__ W, const float* __restrict__ bode,
    const float* __restrict__ w3c, const float* __restrict__ w4c, const float* __restrict__ w5c,
    float* __restrict__ Bm, float* __restrict__ c1,
    unsigned short* __restrict__ slab, unsigned* __restrict__ featbuf) {
  __shared__ float r1[256], r2[256], r3[256], red[4];
  const int tid = threadIdx.x, blk = blockIdx.x;
  if (blk < 256) {
    const int i = blk;
    r1[tid] = W[i * 256 + tid];
    __syncthreads();
    const float v2 = dotcol64(r1, W, tid);   // W^2[i][tid]
    r2[tid] = v2;
    __syncthreads();
    const float v3 = dotcol64(r2, W, tid);   // W^3[i][tid]
    r3[tid] = v3;
    __syncthreads();
    const float v4 = dotcol64(r3, W, tid);   // W^4[i][tid]
    const float w1 = r1[tid];
    Bm[i * 256 + tid] = 0.1f * w1 + 0.005f * v2
                      + (0.001f / 6.f) * v3 + (0.0001f / 24.f) * v4;
    // c1[i] = 0.1*(b[i] + sum_k b[k]*(0.05 W[i,k] + (0.01/6) W2[i,k] + (0.001/24) W3[i,k]))
    const float q = 0.05f * w1 + (0.01f / 6.f) * v2 + (0.001f / 24.f) * v3;
    float val = bode[tid] * q;
#pragma unroll
    for (int off = 32; off > 0; off >>= 1) val += __shfl_down(val, off);
    if ((tid & 63) == 0) red[tid >> 6] = val;
    __syncthreads();
    if (tid == 0) c1[i] = 0.1f * (bode[i] + ((red[0] + red[1]) + (red[2] + red[3])));
  } else {
    const int base = (blk - 256) * 256 + tid;   // 0..98303
#pragma unroll
    for (int u = 0; u < 4; ++u) {
      int e = base + u * 98304;                 // covers 0..393215 = 12*32768
      int s = e >> 15, r = e & 32767;
      int o = r >> 8, kd = r & 255;             // consecutive lane = consecutive kd
      const float* w; int k, j;
      if (s < 3)      { w = w3c; k = 3; j = s; }
      else if (s < 7) { w = w4c; k = 4; j = s - 3; }
      else            { w = w5c; k = 5; j = s - 7; }
      float val = w[(o * 256 + kd) * k + j];    // w[o][d=kd][j], shape (128,256,k)
      int kc = kd >> 5, quad = (kd >> 3) & 3, q8 = kd & 7;
      slab[s * 32768 + ((kc * 4 + quad) * 128 + o) * 8 + q8] = f2bf(val);
    }
    if (base < 64 * 640) featbuf[base] = 0u;
  }
}

// ---- d2a: block i: D[i] = 2B[i] + B^2[i] (1 pass); c1b[i] = 2c1[i] + dot(B[i],c1).
__global__ __launch_bounds__(256) void k_prep2a(
    const float* __restrict__ Bm, const float* __restrict__ c1v,
    float* __restrict__ Dm, float* __restrict__ c1b) {
  __shared__ float r1[256], c1s[256], red[4];
  const int tid = threadIdx.x, i = blockIdx.x;
  r1[tid] = Bm[i * 256 + tid];
  c1s[tid] = c1v[tid];
  __syncthreads();
  const float v2 = dotcol64(r1, Bm, tid);      // B^2[i][tid]
  Dm[i * 256 + tid] = 2.f * r1[tid] + v2;
  float pd = r1[tid] * c1s[tid];
#pragma unroll
  for (int off = 32; off > 0; off >>= 1) pd += __shfl_down(pd, off);
  if ((tid & 63) == 0) red[tid >> 6] = pd;
  __syncthreads();
  if (tid == 0) c1b[i] = 2.f * c1s[i] + ((red[0] + red[1]) + (red[2] + red[3]));
}

// ---- d2b: block i: chain D[i] -> D^5[i] (4 passes, Y=D read-only).
// n10 = I + 5D + 10D^2 + 10D^3 + 5D^4 + D^5 ; scatter row to slab node slices.
// ct  = 5 c1b[i] + 10 dot(D,c1b) + 10 dot(D^2,c1b) + 5 dot(D^3,c1b) + dot(D^4,c1b).
__global__ __launch_bounds__(256) void k_prep2b(
    const float* __restrict__ Dm, const float* __restrict__ c1bv,
    float* __restrict__ c10, unsigned short* __restrict__ slab) {
  __shared__ float curs[256], cbs[256], red[4];
  const int tid = threadIdx.x, i = blockIdx.x;
  const float coefN[6] = {1.f, 5.f, 10.f, 10.f, 5.f, 1.f};   // C(5,k)
  const float coefC[5] = {5.f, 10.f, 10.f, 5.f, 1.f};        // C(5,k+1)
  float v = Dm[i * 256 + tid];
  curs[tid] = v;
  cbs[tid] = c1bv[tid];
  __syncthreads();
  float n10 = ((i == tid) ? 1.f : 0.f) + coefN[1] * v;
  float pd = v * cbs[tid];
#pragma unroll
  for (int off = 32; off > 0; off >>= 1) pd += __shfl_down(pd, off);
  if ((tid & 63) == 0) red[tid >> 6] = pd;
  __syncthreads();
  float ct = coefC[0] * cbs[i] + coefC[1] * ((red[0] + red[1]) + (red[2] + red[3]));

#pragma unroll 1
  for (int k = 2; k <= 5; ++k) {
    v = dotcol64(curs, Dm, tid);        // D^k[i][tid]
    __syncthreads();                    // all reads of curs done
    curs[tid] = v;
    n10 = fmaf(coefN[k], v, n10);
    float pdk = v * cbs[tid];
#pragma unroll
    for (int off = 32; off > 0; off >>= 1) pdk += __shfl_down(pdk, off);
    if ((tid & 63) == 0) red[tid >> 6] = pdk;
    __syncthreads();                    // red ready; curs visible
    if (k <= 4) ct = fmaf(coefC[k], (red[0] + red[1]) + (red[2] + red[3]), ct);
  }

  // scatter n10: element (kd=tid, o=i) of the node B-matrix (P10[kd][o]=N10[o][kd])
  {
    const int o = i, kd = tid;
    const int kc = kd >> 5, quad = (kd >> 3) & 3, q8 = kd & 7;
    slab[(12 + (o >> 7)) * 32768 + ((kc * 4 + quad) * 128 + (o & 127)) * 8 + q8] = f2bf(n10);
  }
  if (tid == 0) c10[i] = ct;
}

// ---------------- fused main kernel ----------------
// grid 1024 = 64 batches x 16 t-chunks of 32 (batch-major: b = blk & 63, so
// all 16 chunks of a batch land on XCD b%8 -> emb gather is L2-local).
// 256 threads = 4 waves; 4 blocks/CU (launch_bounds min 4 waves/SIMD).
// LDS: X tile 36 x 264 bf16 (~19KB). B-fragments direct from slab, depth-2
// register pipeline (R10 body); T5 setprio around MFMA cluster.

__global__ __launch_bounds__(256, 4) void k_main(
    const int* __restrict__ ids, const float* __restrict__ emb,
    const unsigned short* __restrict__ slab, const float* __restrict__ ctot,
    const float* __restrict__ b3, const float* __restrict__ g3, const float* __restrict__ be3,
    const float* __restrict__ b4, const float* __restrict__ g4, const float* __restrict__ be4,
    const float* __restrict__ b5, const float* __restrict__ g5, const float* __restrict__ be5,
    unsigned* __restrict__ featbuf) {
  __shared__ alignas(16) unsigned short Xt[36 * 264];
  __shared__ int ids_s[36];
  const int tid = threadIdx.x;
  const int blk = blockIdx.x;
  const int b = blk & 63;            // batch-major: chunks of b share an XCD
  const int t0 = (blk >> 6) * 32;
  const int lane = tid & 63;
  const int wave = tid >> 6;
  const int m15 = lane & 15;
  const int quad = lane >> 4;

  if (tid < 36) {
    int t = t0 + tid;
    ids_s[tid] = (t < 512) ? ids[b * 512 + t] : -1;
  }
  __syncthreads();
  // gather + fp32->bf16 X tile (rows beyond S zero-filled); 9 iters
  for (int i = tid; i < 36 * 64; i += 256) {
    int row = i >> 6, s4 = i & 63;
    uint2 v = make_uint2(0u, 0u);
    int id = ids_s[row];
    if (id >= 0) {
      const float4 f = *(const float4*)(emb + (size_t)id * 256 + s4 * 4);
      v.x = (unsigned)f2bf(f.x) | ((unsigned)f2bf(f.y) << 16);
      v.y = (unsigned)f2bf(f.z) | ((unsigned)f2bf(f.w) << 16);
    }
    *(uint2*)&Xt[row * 264 + s4 * 4] = v;
  }
  __syncthreads();  // Xt ready; no further barriers

  // per-lane B-fragment bases (bf16 units); frag(e,kc2,nt) = fb[nt] + e*8192 + kc2*4096
  const unsigned short* fb0 = slab + ((size_t)quad * 128 + (wave * 2 + 0) * 16 + m15) * 8;
  const unsigned short* fb1 = fb0 + 128;   // nt=1: +16*8

  bf16x8 fA[4], fB[4];   // [kc2*2+nt]
#pragma unroll
  for (int q = 0; q < 4; ++q) {
    fA[q] = *(const bf16x8*)(((q & 1) ? fb1 : fb0) + (q >> 1) * 4096);
    fB[q] = *(const bf16x8*)(((q & 1) ? fb1 : fb0) + 8192 + (q >> 1) * 4096);
  }

  f32x4 acc[2][2];
#pragma unroll
  for (int mt = 0; mt < 2; ++mt)
#pragma unroll
    for (int nt = 0; nt < 2; ++nt) acc[mt][nt] = (f32x4){0.f, 0.f, 0.f, 0.f};

#define ENTRY(KCQ, FR)                                                          \
  {                                                                             \
    __builtin_amdgcn_s_setprio(1);                                              \
    _Pragma("unroll")                                                           \
    for (int kc2 = 0; kc2 < 2; ++kc2) {                                         \
      const int kd0 = ((KCQ) * 2 + kc2) * 32 + quad * 8;                        \
      bf16x8 af[2];                                                             \
      _Pragma("unroll")                                                         \
      for (int mt = 0; mt < 2; ++mt)                                            \
        af[mt] = *(const bf16x8*)&Xt[(shift + mt * 16 + m15) * 264 + kd0];      \
      _Pragma("unroll")                                                         \
      for (int mt = 0; mt < 2; ++mt) {                                          \
        acc[mt][0] = __builtin_amdgcn_mfma_f32_16x16x32_bf16(af[mt], FR[kc2 * 2 + 0], acc[mt][0], 0, 0, 0); \
        acc[mt][1] = __builtin_amdgcn_mfma_f32_16x16x32_bf16(af[mt], FR[kc2 * 2 + 1], acc[mt][1], 0, 0, 0); \
      }                                                                         \
    }                                                                           \
    __builtin_amdgcn_s_setprio(0);                                              \
  }

  for (int ep = 0; ep < 28; ++ep) {
    const int e0 = ep * 2;
    const int slice = e0 >> 2;             // e0,e0+1 share slice (e0 even)
    const int shift = (slice < 3) ? slice
                    : (slice < 7) ? (slice - 3)
                    : (slice < 12) ? (slice - 7) : 0;
    const int kcq0 = e0 & 3;

    ENTRY(kcq0, fA);
    if (ep < 27) {
      const int eo = (e0 + 2) * 8192;
#pragma unroll
      for (int q = 0; q < 4; ++q)
        fA[q] = *(const bf16x8*)(((q & 1) ? fb1 : fb0) + eo + (q >> 1) * 4096);
    }
    ENTRY(kcq0 + 1, fB);
    if (ep < 27) {
      const int eo = (e0 + 3) * 8192;
#pragma unroll
      for (int q = 0; q < 4; ++q)
        fB[q] = *(const bf16x8*)(((q & 1) ? fb1 : fb0) + eo + (q >> 1) * 4096);
    }

    // epilogue at group boundaries: ep 5 (conv3), 13 (conv4), 23 (conv5),
    // 25 (node lo), 27 (node hi)
    const int g = (ep == 5) ? 0 : (ep == 13) ? 1 : (ep == 23) ? 2
                : (ep == 25) ? 3 : (ep == 27) ? 4 : -1;
    if (g >= 0) {
      if (g < 3) {
        const int kk = g + 3;
        const float* bb  = (g == 0) ? b3 : (g == 1) ? b4 : b5;
        const float* gg  = (g == 0) ? g3 : (g == 1) ? g4 : g5;
        const float* bbe = (g == 0) ? be3 : (g == 1) ? be4 : be5;
        const int off = 256 + g * 128;     // feats: [node 256][p3 128][p4 128][p5 128]
        const int tmax = 512 - kk;
#pragma unroll
        for (int nt = 0; nt < 2; ++nt) {
          const int n = (wave * 2 + nt) * 16 + m15;
          const float sc = gg[n] * 0.9999950000375f;  // g * 1/sqrt(1+1e-5)
          const float sh = fmaf(sc, bb[n], bbe[n]);
          float mx = 0.f;  // relu floor doubles as init
#pragma unroll
          for (int mt = 0; mt < 2; ++mt)
#pragma unroll
            for (int r = 0; r < 4; ++r) {
              const int t = t0 + mt * 16 + quad * 4 + r;
              const float v = fmaf(sc, acc[mt][nt][r], sh);
              if (t <= tmax) mx = fmaxf(mx, v);
            }
          mx = fmaxf(mx, __shfl_xor(mx, 16));
          mx = fmaxf(mx, __shfl_xor(mx, 32));
          if (quad == 0) atomicMax(&featbuf[b * 640 + off + n], __float_as_uint(mx));
        }
      } else {
        const int base = (g == 3) ? 0 : 128;
#pragma unroll
        for (int nt = 0; nt < 2; ++nt) {
          const int n = (wave * 2 + nt) * 16 + m15;
          const float ct = ctot[base + n];
          float mx = -3.4e38f;
#pragma unroll
          for (int mt = 0; mt < 2; ++mt)
#pragma unroll
            for (int r = 0; r < 4; ++r)
              mx = fmaxf(mx, acc[mt][nt][r] + ct);
          mx = fmaxf(mx, __shfl_xor(mx, 16));
          mx = fmaxf(mx, __shfl_xor(mx, 32));
          if (quad == 0) {
            unsigned bits = __float_as_uint(mx);
            unsigned key = (bits & 0x80000000u) ? ~bits : (bits | 0x80000000u);  // order-preserving
            atomicMax(&featbuf[b * 640 + base + n], key);
          }
        }
      }
      // reset accumulators for the next group
#pragma unroll
      for (int mt = 0; mt < 2; ++mt)
#pragma unroll
        for (int nt = 0; nt < 2; ++nt) acc[mt][nt] = (f32x4){0.f, 0.f, 0.f, 0.f};
    }
  }
#undef ENTRY
}

// ---------------- classifier ----------------
__global__ void k_fin(const unsigned* __restrict__ featbuf, const float* __restrict__ wc,
                      const float* __restrict__ bc, float* __restrict__ out) {
  int b = blockIdx.x, lane = threadIdx.x;  // 64 threads = 1 wave
  float p[10];
#pragma unroll
  for (int c = 0; c < 10; ++c) p[c] = 0.f;
  for (int f = lane; f < 640; f += 64) {
    unsigned u = featbuf[b * 640 + f];
    float v;
    if (f < 256) v = (u & 0x80000000u) ? __uint_as_float(u ^ 0x80000000u) : __uint_as_float(~u);
    else v = __uint_as_float(u);
#pragma unroll
    for (int c = 0; c < 10; ++c) p[c] = fmaf(v, wc[c * 640 + f], p[c]);
  }
#pragma unroll
  for (int c = 0; c < 10; ++c) {
    float s = p[c];
#pragma unroll
    for (int off = 32; off > 0; off >>= 1) s += __shfl_down(s, off);
    if (lane == 0) out[b * 10 + c] = s + bc[c];
  }
}

// ---------------- launcher ----------------
extern "C" void kernel_launch(void* const* d_in, const int* in_sizes, int n_in,
                              void* d_out, int out_size, void* d_ws, size_t ws_size,
                              hipStream_t stream) {
  (void)in_sizes; (void)n_in; (void)out_size; (void)ws_size;
  const int*   ids  = (const int*)d_in[0];
  const float* emb  = (const float*)d_in[1];
  const float* W    = (const float*)d_in[2];
  const float* bode = (const float*)d_in[3];
  const float* w3   = (const float*)d_in[4];
  const float* b3   = (const float*)d_in[5];
  const float* g3   = (const float*)d_in[6];
  const float* be3  = (const float*)d_in[7];
  const float* w4   = (const float*)d_in[8];
  const float* b4   = (const float*)d_in[9];
  const float* g4   = (const float*)d_in[10];
  const float* be4  = (const float*)d_in[11];
  const float* w5   = (const float*)d_in[12];
  const float* b5   = (const float*)d_in[13];
  const float* g5   = (const float*)d_in[14];
  const float* be5  = (const float*)d_in[15];
  const float* wc   = (const float*)d_in[16];
  const float* bc   = (const float*)d_in[17];
  float* out = (float*)d_out;

  float* wsf = (float*)d_ws;
  // ws layout (floats): Bm 0 | Dm 65536 | c1 131072 | c1b 131328 | c10 131584 |
  // slab 131840 (14*32768 bf16 = 229376 floats) | featbuf 361216 (40960 uints)
  float* Bm  = wsf;
  float* Dm  = wsf + 65536;
  float* c1  = wsf + 131072;
  float* c1b = wsf + 131328;
  float* c10 = wsf + 131584;
  unsigned short* slab = (unsigned short*)(wsf + 131840);
  unsigned* featbuf = (unsigned*)(wsf + 361216);

  hipLaunchKernelGGL(k_prep1, dim3(640), dim3(256), 0, stream,
                     W, bode, w3, w4, w5, Bm, c1, slab, featbuf);
  hipLaunchKernelGGL(k_prep2a, dim3(256), dim3(256), 0, stream, Bm, c1, Dm, c1b);
  hipLaunchKernelGGL(k_prep2b, dim3(256), dim3(256), 0, stream, Dm, c1b, c10, slab);
  hipLaunchKernelGGL(k_main, dim3(1024), dim3(256), 0, stream,
                     ids, emb, slab, c10,
                     b3, g3, be3, b4, g4, be4, b5, g5, be5, featbuf);
  hipLaunchKernelGGL(k_fin, dim3(64), dim3(64), 0, stream, featbuf, wc, bc, out);
}